// Round 1
// baseline (321.752 us; speedup 1.0000x reference)
//
#include <hip/hip_runtime.h>

// Bilinear 2x upsample, NHWC fp32.
// in : (8, 256, 256, 32)  = 64 MiB
// out: (8, 512, 512, 32)  = 256 MiB
// One thread per float4 of output channels -> 8*512*512*8 = 16,777,216 threads.
// Thread id decomposition (c4 innermost) keeps all loads/stores 16B-coalesced.

#define IH 256
#define IW 256
#define OHW 512
#define C4 8        // 32 channels / 4 floats per float4

__global__ __launch_bounds__(256) void bilinear2x_kernel(
    const float* __restrict__ img, float* __restrict__ out) {
    unsigned tid = blockIdx.x * 256u + threadIdx.x;

    unsigned c4 = tid & (C4 - 1);          // float4 index within channels
    unsigned ox = (tid >> 3) & (OHW - 1);
    unsigned oy = (tid >> 12) & (OHW - 1);
    unsigned n  = tid >> 21;

    // scale = 0.5: g = max((o+0.5)*0.5 - 0.5, 0) = max(0.5*o - 0.25, 0)
    float gy = fmaxf(0.5f * (float)oy - 0.25f, 0.0f);
    float gx = fmaxf(0.5f * (float)ox - 0.25f, 0.0f);
    int y0 = (int)gy;                      // gy >= 0 -> trunc == floor
    int x0 = (int)gx;
    float h0 = gy - (float)y0;
    float w0 = gx - (float)x0;
    int y1 = y0 + (y0 < IH - 1);
    int x1 = x0 + (x0 < IW - 1);
    float h1 = 1.0f - h0, w1 = 1.0f - w0;

    const float4* base = (const float4*)img;
    // strides in float4 units: x -> 8, y -> IW*8, n -> IH*IW*8
    size_t nb = (size_t)n * (IH * IW * C4);
    size_t r0 = nb + (size_t)y0 * (IW * C4);
    size_t r1 = nb + (size_t)y1 * (IW * C4);

    float4 v00 = base[r0 + (size_t)x0 * C4 + c4];
    float4 v01 = base[r0 + (size_t)x1 * C4 + c4];
    float4 v10 = base[r1 + (size_t)x0 * C4 + c4];
    float4 v11 = base[r1 + (size_t)x1 * C4 + c4];

    float c00 = h1 * w1, c01 = h1 * w0, c10 = h0 * w1, c11 = h0 * w0;
    float4 r;
    r.x = c00 * v00.x + c01 * v01.x + c10 * v10.x + c11 * v11.x;
    r.y = c00 * v00.y + c01 * v01.y + c10 * v10.y + c11 * v11.y;
    r.z = c00 * v00.z + c01 * v01.z + c10 * v10.z + c11 * v11.z;
    r.w = c00 * v00.w + c01 * v01.w + c10 * v10.w + c11 * v11.w;

    ((float4*)out)[tid] = r;
}

extern "C" void kernel_launch(void* const* d_in, const int* in_sizes, int n_in,
                              void* d_out, int out_size, void* d_ws, size_t ws_size,
                              hipStream_t stream) {
    const float* img = (const float*)d_in[0];
    float* out = (float*)d_out;
    // total float4s of output: 8*512*512*8 = 16,777,216
    const unsigned total = 8u * 512u * 512u * 8u;
    dim3 grid(total / 256u);
    dim3 block(256);
    bilinear2x_kernel<<<grid, block, 0, stream>>>(img, out);
}

// Round 2
// 309.198 us; speedup vs baseline: 1.0406x; 1.0406x over previous
//
#include <hip/hip_runtime.h>

// Bilinear 2x upsample, NHWC fp32.
// in : (8, 256, 256, 32)  = 64 MiB
// out: (8, 512, 512, 32)  = 256 MiB
//
// R2: each thread produces TWO output pixels (oy = 2j, 2j+1) at one (ox, c4).
// They share input rows {j-1, j, j+1}: 6 float4 loads + 2 float4 stores per
// thread (vs 8 loads / 2 stores across two threads in R1). y-weights are the
// constants {0.25, 0.75} (with row-clamp reproducing the edge semantics
// exactly). Stores remain perfectly wave-coalesced (c4 innermost).

#define IH 256
#define IW 256
#define OHW 512
#define C4 8        // 32 channels / 4 floats per float4

__global__ __launch_bounds__(256) void bilinear2x_kernel(
    const float* __restrict__ img, float* __restrict__ out) {
    unsigned tid = blockIdx.x * 256u + threadIdx.x;

    unsigned c4 = tid & (C4 - 1);          // float4 index within channels
    unsigned ox = (tid >> 3) & (OHW - 1);  // output x
    unsigned j  = (tid >> 12) & (IH - 1);  // output y pair index: oy = 2j, 2j+1
    unsigned n  = tid >> 20;

    // x weights: gx = max(0.5*ox - 0.25, 0)
    float gx = fmaxf(0.5f * (float)ox - 0.25f, 0.0f);
    int x0 = (int)gx;                      // trunc == floor (gx >= 0)
    float w0 = gx - (float)x0;
    int x1 = x0 + (x0 < IW - 1);
    float w1 = 1.0f - w0;

    // input rows j-1, j, j+1 (clamped). Clamping reproduces the reference
    // edge cases: j=0 -> even output = row0 exactly (0.25*r0+0.75*r0);
    // j=255 -> odd output = row255 exactly.
    int rA = (int)j - 1; rA = rA < 0 ? 0 : rA;
    int rB = (int)j;
    int rC = (int)j + 1; rC = rC > IH - 1 ? IH - 1 : rC;

    const float4* base = (const float4*)img;
    size_t nb = (size_t)n * (IH * IW * C4);
    const float4* pA = base + nb + (size_t)rA * (IW * C4);
    const float4* pB = base + nb + (size_t)rB * (IW * C4);
    const float4* pC = base + nb + (size_t)rC * (IW * C4);
    size_t o0 = (size_t)x0 * C4 + c4;
    size_t o1 = (size_t)x1 * C4 + c4;

    float4 a0 = pA[o0], a1 = pA[o1];
    float4 b0 = pB[o0], b1 = pB[o1];
    float4 c0 = pC[o0], c1 = pC[o1];

    // x-interpolate each row
    float4 ra, rb, rc;
    ra.x = w1 * a0.x + w0 * a1.x;  ra.y = w1 * a0.y + w0 * a1.y;
    ra.z = w1 * a0.z + w0 * a1.z;  ra.w = w1 * a0.w + w0 * a1.w;
    rb.x = w1 * b0.x + w0 * b1.x;  rb.y = w1 * b0.y + w0 * b1.y;
    rb.z = w1 * b0.z + w0 * b1.z;  rb.w = w1 * b0.w + w0 * b1.w;
    rc.x = w1 * c0.x + w0 * c1.x;  rc.y = w1 * c0.y + w0 * c1.y;
    rc.z = w1 * c0.z + w0 * c1.z;  rc.w = w1 * c0.w + w0 * c1.w;

    // y-combine with constant weights:
    // even (oy=2j):   0.25*rowA + 0.75*rowB
    // odd  (oy=2j+1): 0.75*rowB + 0.25*rowC
    float4 re, ro;
    re.x = 0.25f * ra.x + 0.75f * rb.x;  re.y = 0.25f * ra.y + 0.75f * rb.y;
    re.z = 0.25f * ra.z + 0.75f * rb.z;  re.w = 0.25f * ra.w + 0.75f * rb.w;
    ro.x = 0.75f * rb.x + 0.25f * rc.x;  ro.y = 0.75f * rb.y + 0.25f * rc.y;
    ro.z = 0.75f * rb.z + 0.25f * rc.z;  ro.w = 0.75f * rb.w + 0.25f * rc.w;

    // stores: out[(n, 2j, ox, c4)] and out[(n, 2j+1, ox, c4)]
    float4* ob = (float4*)out;
    size_t oe = (((size_t)n * OHW + 2 * j) * OHW + ox) * C4 + c4;
    ob[oe] = re;
    ob[oe + (size_t)OHW * C4] = ro;
}

extern "C" void kernel_launch(void* const* d_in, const int* in_sizes, int n_in,
                              void* d_out, int out_size, void* d_ws, size_t ws_size,
                              hipStream_t stream) {
    const float* img = (const float*)d_in[0];
    float* out = (float*)d_out;
    // threads: 8 * 256(j) * 512(ox) * 8(c4) = 8,388,608
    const unsigned total = 8u * 256u * 512u * 8u;
    dim3 grid(total / 256u);
    dim3 block(256);
    bilinear2x_kernel<<<grid, block, 0, stream>>>(img, out);
}